// Round 1
// baseline (413.899 us; speedup 1.0000x reference)
//
#include <hip/hip_runtime.h>
#include <hip/hip_bf16.h>

// SelfAttention: qp = q@Wq^T+bq; kp,vp likewise; E = qp kp^T/sqrt(1024);
// P = softmax(E); out = P vp.   B=4, S=2048, D=1024, fp32 in/out.
//
// Strategy: everything through bf16 MFMA (no fp32 MFMA on CDNA4).
// One BT-layout GEMM template (A [M,K] row-major, B [N,K] row-major),
// 128x128 tile, BK=32, 4 waves, reg-staged (folds fp32->bf16 convert),
// double-buffered XOR-swizzled LDS (conflict-free b128 reads/writes).
// vp is transposed once so PV is also BT layout.
//
// Workspace layout (96 MB):
//   qp  bf16 [4,2048,1024] @ 0MB
//   kp  bf16 [4,2048,1024] @ 16MB
//   vp  bf16 [4,2048,1024] @ 32MB
//   vpT bf16 [4,1024,2048] @ 48MB
//   P   bf16 [4,2048,2048] @ 64MB   (E overwritten in-place by softmax)

typedef __attribute__((ext_vector_type(8))) short short8;
typedef __attribute__((ext_vector_type(4))) float f32x4;

// bijective XOR swizzle on a [128 rows x 64B] LDS tile: spreads the
// stride-64B rows across banks; bits 4..6 ^= row bits 0..2 (triangular -> bijective).
static __device__ __forceinline__ int swz(int b) {
    return b ^ (((b >> 6) & 7) << 4);
}

static __device__ __forceinline__ unsigned short f2bf(float f) {
    unsigned u = __float_as_uint(f);
    u += 0x7FFFu + ((u >> 16) & 1u);   // round-to-nearest-even
    return (unsigned short)(u >> 16);
}

static __device__ __forceinline__ float bf2f(unsigned short s) {
    return __uint_as_float(((unsigned)s) << 16);
}

// Load 16 contiguous elements starting at g, as bf16 bit-patterns.
template <typename T>
static __device__ __forceinline__ void load16bf(const T* __restrict__ g, short8& lo, short8& hi) {
    if constexpr (sizeof(T) == 4) {
        const f32x4* p = reinterpret_cast<const f32x4*>(g);
        f32x4 a = p[0], b = p[1], c = p[2], d = p[3];
#pragma unroll
        for (int j = 0; j < 4; ++j) lo[j]     = (short)f2bf(a[j]);
#pragma unroll
        for (int j = 0; j < 4; ++j) lo[4 + j] = (short)f2bf(b[j]);
#pragma unroll
        for (int j = 0; j < 4; ++j) hi[j]     = (short)f2bf(c[j]);
#pragma unroll
        for (int j = 0; j < 4; ++j) hi[4 + j] = (short)f2bf(d[j]);
    } else {
        const short8* p = reinterpret_cast<const short8*>(g);
        lo = p[0];
        hi = p[1];
    }
}

// C = scale * (A @ B^T) + bias.  A: [M,K] (TA = float|ushort-bf16),
// B: [N,K] (TB likewise), C: bf16 or fp32 [M,N]. blockIdx.z batches via strides.
template <typename TA, typename TB, bool OUT_BF16, bool HAS_BIAS>
__global__ __launch_bounds__(256) void gemm_bt(
    const TA* __restrict__ A, const TB* __restrict__ B,
    const float* __restrict__ bias, void* __restrict__ Cv,
    int M, int N, int K, long sA, long sB, long sC, float scale)
{
    __shared__ __align__(16) char lds[2][2][128 * 64];  // [buf][A/B][128 rows x 32 bf16]
    const int tid = threadIdx.x;
    const long bz = blockIdx.z;
    A += bz * sA;
    B += bz * sB;
    const int row0 = blockIdx.y * 128, col0 = blockIdx.x * 128;

    // staging: thread t handles row r = t>>1, k-half h = t&1 (16 elems)
    const int r = tid >> 1, h = tid & 1;
    const TA* ga = A + (long)(row0 + r) * K + h * 16;
    const TB* gb = B + (long)(col0 + r) * K + h * 16;
    const int w0 = swz(r * 64 + h * 32);
    const int w1 = swz(r * 64 + h * 32 + 16);

    const int lane = tid & 63, wid = tid >> 6;
    const int wr = wid >> 1, wc = wid & 1;       // 2x2 wave grid, 64x64 per wave
    const int fq = lane >> 4, fr = lane & 15;

    int ra[4], rb[4];
#pragma unroll
    for (int i = 0; i < 4; ++i) {
        ra[i] = swz((wr * 64 + i * 16 + fr) * 64 + fq * 16);
        rb[i] = swz((wc * 64 + i * 16 + fr) * 64 + fq * 16);
    }

    f32x4 acc[4][4] = {};

    const int KT = K >> 5;
    short8 la0, la1, lb0, lb1;
    load16bf(ga, la0, la1);
    load16bf(gb, lb0, lb1);
    *(short8*)(&lds[0][0][0] + w0) = la0;
    *(short8*)(&lds[0][0][0] + w1) = la1;
    *(short8*)(&lds[0][1][0] + w0) = lb0;
    *(short8*)(&lds[0][1][0] + w1) = lb1;
    __syncthreads();

    for (int kt = 0; kt < KT; ++kt) {
        const int cur = kt & 1;
        const bool more = (kt + 1 < KT);
        if (more) {  // issue next-tile global loads before compute (overlap)
            load16bf(ga + (kt + 1) * 32, la0, la1);
            load16bf(gb + (kt + 1) * 32, lb0, lb1);
        }
        char* pa = &lds[cur][0][0];
        char* pb = &lds[cur][1][0];
        short8 af[4], bfg[4];
#pragma unroll
        for (int i = 0; i < 4; ++i) af[i] = *(const short8*)(pa + ra[i]);
#pragma unroll
        for (int i = 0; i < 4; ++i) bfg[i] = *(const short8*)(pb + rb[i]);
#pragma unroll
        for (int mi = 0; mi < 4; ++mi)
#pragma unroll
            for (int ni = 0; ni < 4; ++ni)
                acc[mi][ni] = __builtin_amdgcn_mfma_f32_16x16x32_bf16(
                    af[mi], bfg[ni], acc[mi][ni], 0, 0, 0);
        if (more) {  // write next buffer (other half of double buffer)
            char* qa = &lds[cur ^ 1][0][0];
            char* qb = &lds[cur ^ 1][1][0];
            *(short8*)(qa + w0) = la0;
            *(short8*)(qa + w1) = la1;
            *(short8*)(qb + w0) = lb0;
            *(short8*)(qb + w1) = lb1;
        }
        __syncthreads();
    }

    float bcol[4];
#pragma unroll
    for (int ni = 0; ni < 4; ++ni)
        bcol[ni] = HAS_BIAS ? bias[col0 + wc * 64 + ni * 16 + fr] : 0.f;

    // C/D layout (m89-verified): col = lane&15, row = (lane>>4)*4 + j
#pragma unroll
    for (int mi = 0; mi < 4; ++mi) {
#pragma unroll
        for (int ni = 0; ni < 4; ++ni) {
            const int cc = col0 + wc * 64 + ni * 16 + fr;
#pragma unroll
            for (int j = 0; j < 4; ++j) {
                const int rr = row0 + wr * 64 + mi * 16 + fq * 4 + j;
                const float vv = acc[mi][ni][j] * scale + bcol[ni];
                if constexpr (OUT_BF16) {
                    ((unsigned short*)Cv)[bz * sC + (long)rr * N + cc] = f2bf(vv);
                } else {
                    ((float*)Cv)[bz * sC + (long)rr * N + cc] = vv;
                }
            }
        }
    }
}

// In-place row softmax on bf16 [rows][S], S = 2048, one block (256 thr) per row.
__global__ __launch_bounds__(256) void softmax_rows(unsigned short* __restrict__ P, int S) {
    const long row = blockIdx.x;
    unsigned short* p = P + row * (long)S;
    const int tid = threadIdx.x;
    const int wid = tid >> 6, lane = tid & 63;

    short8 v = *(const short8*)(p + tid * 8);
    float x[8];
#pragma unroll
    for (int j = 0; j < 8; ++j) x[j] = bf2f((unsigned short)v[j]);

    float m = x[0];
#pragma unroll
    for (int j = 1; j < 8; ++j) m = fmaxf(m, x[j]);
#pragma unroll
    for (int off = 32; off > 0; off >>= 1) m = fmaxf(m, __shfl_xor(m, off));
    __shared__ float red[8];
    if (lane == 0) red[wid] = m;
    __syncthreads();
    m = fmaxf(fmaxf(red[0], red[1]), fmaxf(red[2], red[3]));

    float e[8], s = 0.f;
#pragma unroll
    for (int j = 0; j < 8; ++j) { e[j] = __expf(x[j] - m); s += e[j]; }
#pragma unroll
    for (int off = 32; off > 0; off >>= 1) s += __shfl_xor(s, off);
    if (lane == 0) red[4 + wid] = s;
    __syncthreads();
    s = red[4] + red[5] + red[6] + red[7];
    const float inv = 1.f / s;

    short8 o;
#pragma unroll
    for (int j = 0; j < 8; ++j) o[j] = (short)f2bf(e[j] * inv);
    *(short8*)(p + tid * 8) = o;
}

// bf16 transpose: in [z][R][C] -> out [z][C][R], 64x64 LDS tiles.
__global__ __launch_bounds__(256) void transpose_bf16(
    const unsigned short* __restrict__ in, unsigned short* __restrict__ out, int R, int C)
{
    __shared__ unsigned short t[64][72];  // +8 pad breaks column-read conflicts
    const long z = blockIdx.z;
    in  += z * (long)R * C;
    out += z * (long)R * C;
    const int r0 = blockIdx.y * 64, c0 = blockIdx.x * 64;
    const int tid = threadIdx.x;

    const int r = tid >> 2, cc = (tid & 3) * 16;
    const short8* src = (const short8*)(in + (long)(r0 + r) * C + c0 + cc);
    short8 v0 = src[0], v1 = src[1];
#pragma unroll
    for (int j = 0; j < 8; ++j) {
        t[r][cc + j]     = (unsigned short)v0[j];
        t[r][cc + 8 + j] = (unsigned short)v1[j];
    }
    __syncthreads();

    const int c = tid >> 2, rr = (tid & 3) * 16;
    short8 o0, o1;
#pragma unroll
    for (int j = 0; j < 8; ++j) {
        o0[j] = (short)t[rr + j][c];
        o1[j] = (short)t[rr + 8 + j][c];
    }
    short8* dst = (short8*)(out + (long)(c0 + c) * R + r0 + rr);
    dst[0] = o0;
    dst[1] = o1;
}

extern "C" void kernel_launch(void* const* d_in, const int* in_sizes, int n_in,
                              void* d_out, int out_size, void* d_ws, size_t ws_size,
                              hipStream_t stream) {
    const float* q  = (const float*)d_in[0];
    const float* k  = (const float*)d_in[1];
    const float* v  = (const float*)d_in[2];
    const float* Wq = (const float*)d_in[3];
    const float* bq = (const float*)d_in[4];
    const float* Wk = (const float*)d_in[5];
    const float* bk = (const float*)d_in[6];
    const float* Wv = (const float*)d_in[7];
    const float* bv = (const float*)d_in[8];

    const int S = 2048, D = 1024;          // B=4 batches
    const long MB = 1024L * 1024L;
    char* ws = (char*)d_ws;
    unsigned short* qp  = (unsigned short*)(ws + 0 * MB);
    unsigned short* kp  = (unsigned short*)(ws + 16 * MB);
    unsigned short* vp  = (unsigned short*)(ws + 32 * MB);
    unsigned short* vpT = (unsigned short*)(ws + 48 * MB);
    unsigned short* P   = (unsigned short*)(ws + 64 * MB);  // 32 MB

    dim3 blk(256);

    // Projections: [8192,1024] @ W[1024,1024]^T + b -> bf16
    gemm_bt<float, float, true, true><<<dim3(8, 64, 1), blk, 0, stream>>>(
        q, Wq, bq, qp, 8192, 1024, 1024, 0, 0, 0, 1.f);
    gemm_bt<float, float, true, true><<<dim3(8, 64, 1), blk, 0, stream>>>(
        k, Wk, bk, kp, 8192, 1024, 1024, 0, 0, 0, 1.f);
    gemm_bt<float, float, true, true><<<dim3(8, 64, 1), blk, 0, stream>>>(
        v, Wv, bv, vp, 8192, 1024, 1024, 0, 0, 0, 1.f);

    // E = qp @ kp^T / sqrt(1024), per batch
    gemm_bt<unsigned short, unsigned short, true, false><<<dim3(16, 16, 4), blk, 0, stream>>>(
        qp, kp, nullptr, P, 2048, 2048, 1024,
        (long)S * D, (long)S * D, (long)S * S, 0.03125f);

    // P = softmax(E) rows, in place
    softmax_rows<<<dim3(4 * S), blk, 0, stream>>>(P, S);

    // vpT[b] = vp[b]^T  ([2048,1024] -> [1024,2048])
    transpose_bf16<<<dim3(16, 32, 4), blk, 0, stream>>>(vp, vpT, S, D);

    // out = P @ vpT^T (fp32 out)
    gemm_bt<unsigned short, unsigned short, false, false><<<dim3(8, 16, 4), blk, 0, stream>>>(
        P, vpT, nullptr, (float*)d_out, 2048, 1024, 2048,
        (long)S * S, (long)D * S, (long)S * D, 1.f);
}

// Round 2
// 390.549 us; speedup vs baseline: 1.0598x; 1.0598x over previous
//
#include <hip/hip_runtime.h>
#include <hip/hip_bf16.h>

// SelfAttention: qp = q@Wq^T+bq (k,v likewise); E = qp kp^T/32; P = softmax(E);
// out = P vp.   B=4, S=2048, D=1024, fp32 in/out.
//
// All GEMMs via bf16 MFMA using the m97 structure: 128x128 tile, BK=32,
// 4 waves, global_load_lds width=16 into linear LDS, 2-barrier K-loop.
// fp32 inputs are pre-converted to bf16 by a memory-bound pass (one 16 MiB
// staging buffer reused for q/k/v; 2 MiB for W). vp transposed once so the
// PV GEMM is BT-layout too.
//
// Workspace (98 MiB):
//   sb   bf16 [8192,1024]  @  0 MiB  (q/k/v staging, reused; vpT later)
//   wb   bf16 [1024,1024]  @ 16 MiB  (Wq/Wk/Wv staging, reused)
//   qp   bf16 [4,2048,1024]@ 18 MiB
//   kp   bf16 [4,2048,1024]@ 34 MiB
//   vp   bf16 [4,2048,1024]@ 50 MiB
//   P    bf16 [4,2048,2048]@ 66 MiB  (E -> softmax in place)
//   vpT  bf16 [4,1024,2048]@  0 MiB  (over sb, which is dead by then)

typedef unsigned short u16;
typedef __attribute__((ext_vector_type(8))) short short8;
typedef __attribute__((ext_vector_type(4))) float f32x4;

typedef const __attribute__((address_space(1))) void* gptr_t;
typedef __attribute__((address_space(3))) void* sptr_t;

static __device__ __forceinline__ u16 f2bf(float f) {
    unsigned u = __float_as_uint(f);
    u += 0x7FFFu + ((u >> 16) & 1u);   // round-to-nearest-even
    return (u16)(u >> 16);
}
static __device__ __forceinline__ float bf2f(u16 s) {
    return __uint_as_float(((unsigned)s) << 16);
}

// async global->LDS, 16B per lane; l must be wave-uniform (lane*16 added by HW)
static __device__ __forceinline__ void gll16(const u16* g, u16* l) {
    __builtin_amdgcn_global_load_lds((gptr_t)g, (sptr_t)l, 16, 0, 0);
}

// fp32 -> bf16 for two tensors (sizes may differ), z selects. 8 elems/thr/iter.
__global__ __launch_bounds__(256) void cvt2(
    const float* __restrict__ a, u16* __restrict__ oa, long na,
    const float* __restrict__ b, u16* __restrict__ ob, long nb)
{
    const float* s = blockIdx.z ? b : a;
    u16* d = blockIdx.z ? ob : oa;
    const long n = blockIdx.z ? nb : na;
    const long stride = (long)gridDim.x * blockDim.x * 8;
    for (long i = ((long)blockIdx.x * blockDim.x + threadIdx.x) * 8; i < n; i += stride) {
        f32x4 x = *(const f32x4*)(s + i);
        f32x4 y = *(const f32x4*)(s + i + 4);
        short8 o;
#pragma unroll
        for (int j = 0; j < 4; ++j) { o[j] = (short)f2bf(x[j]); o[4 + j] = (short)f2bf(y[j]); }
        *(short8*)(d + i) = o;
    }
}

// C = scale * (A @ B^T) + bias.  A: bf16 [M,K], B: bf16 [N,K], C: bf16|fp32 [M,N].
// m97 structure: 128x128 tile, BK=32, 4 waves, global_load_lds(16B), linear LDS.
template <bool OUT_BF16, bool HAS_BIAS>
__global__ __launch_bounds__(256) void gemm_bt(
    const u16* __restrict__ A, const u16* __restrict__ B,
    const float* __restrict__ bias, void* __restrict__ Cv,
    int M, int N, int K, long sA, long sB, long sC, float scale)
{
    __shared__ __align__(16) u16 lA[4096], lB[4096];   // [128 rows][32 k] each
    const int tid = threadIdx.x;
    const long bz = blockIdx.z;
    A += bz * sA;
    B += bz * sB;
    const int row0 = blockIdx.y * 128, col0 = blockIdx.x * 128;
    const int lane = tid & 63, wid = tid >> 6;

    // staging map: LDS byte o = i*4096 + wid*1024 + lane*16 -> row = o>>6, colbyte = o&63
    const int srow = wid * 16 + (lane >> 2);
    const int scol = (lane & 3) * 8;                   // u16 units
    const u16* ga = A + (long)(row0 + srow) * K + scol;
    const u16* gb = B + (long)(col0 + srow) * K + scol;
    const long g1 = 64L * K;                            // issue-1 row offset
    u16* la0 = lA + wid * 512;                          // wave-uniform bases
    u16* la1 = lA + 2048 + wid * 512;
    u16* lb0 = lB + wid * 512;
    u16* lb1 = lB + 2048 + wid * 512;

    const int wr = wid >> 1, wc = wid & 1;              // 2x2 wave grid, 64x64/wave
    const int fq = lane >> 4, fr = lane & 15;
    const u16* pa[4];
    const u16* pb[4];
#pragma unroll
    for (int i = 0; i < 4; ++i) {
        pa[i] = lA + (wr * 64 + i * 16 + fr) * 32 + fq * 8;
        pb[i] = lB + (wc * 64 + i * 16 + fr) * 32 + fq * 8;
    }

    f32x4 acc[4][4] = {};
    const int KT = K >> 5;
    for (int kt = 0; kt < KT; ++kt) {
        const long ko = (long)kt * 32;
        gll16(ga + ko, la0);
        gll16(ga + ko + g1, la1);
        gll16(gb + ko, lb0);
        gll16(gb + ko + g1, lb1);
        __syncthreads();                                // drains vmcnt, loads landed
        short8 af[4], bf[4];
#pragma unroll
        for (int i = 0; i < 4; ++i) af[i] = *(const short8*)pa[i];
#pragma unroll
        for (int i = 0; i < 4; ++i) bf[i] = *(const short8*)pb[i];
#pragma unroll
        for (int mi = 0; mi < 4; ++mi)
#pragma unroll
            for (int ni = 0; ni < 4; ++ni)
                acc[mi][ni] = __builtin_amdgcn_mfma_f32_16x16x32_bf16(
                    af[mi], bf[ni], acc[mi][ni], 0, 0, 0);
        __syncthreads();                                // LDS safe to overwrite
    }

    float bcol[4];
#pragma unroll
    for (int ni = 0; ni < 4; ++ni)
        bcol[ni] = HAS_BIAS ? bias[col0 + wc * 64 + ni * 16 + fr] : 0.f;

    // C/D layout (m89-verified): col = lane&15, row = (lane>>4)*4 + j
#pragma unroll
    for (int mi = 0; mi < 4; ++mi) {
#pragma unroll
        for (int ni = 0; ni < 4; ++ni) {
            const int cc = col0 + wc * 64 + ni * 16 + fr;
#pragma unroll
            for (int j = 0; j < 4; ++j) {
                const int rr = row0 + wr * 64 + mi * 16 + fq * 4 + j;
                const float vv = acc[mi][ni][j] * scale + bcol[ni];
                if constexpr (OUT_BF16) {
                    ((u16*)Cv)[bz * sC + (long)rr * N + cc] = f2bf(vv);
                } else {
                    ((float*)Cv)[bz * sC + (long)rr * N + cc] = vv;
                }
            }
        }
    }
}

// In-place row softmax on bf16 [rows][S], S = 2048, one 256-thr block per row.
__global__ __launch_bounds__(256) void softmax_rows(u16* __restrict__ P, int S) {
    const long row = blockIdx.x;
    u16* p = P + row * (long)S;
    const int tid = threadIdx.x;
    const int wid = tid >> 6, lane = tid & 63;

    short8 v = *(const short8*)(p + tid * 8);
    float x[8];
#pragma unroll
    for (int j = 0; j < 8; ++j) x[j] = bf2f((u16)v[j]);

    float m = x[0];
#pragma unroll
    for (int j = 1; j < 8; ++j) m = fmaxf(m, x[j]);
#pragma unroll
    for (int off = 32; off > 0; off >>= 1) m = fmaxf(m, __shfl_xor(m, off));
    __shared__ float red[8];
    if (lane == 0) red[wid] = m;
    __syncthreads();
    m = fmaxf(fmaxf(red[0], red[1]), fmaxf(red[2], red[3]));

    float e[8], s = 0.f;
#pragma unroll
    for (int j = 0; j < 8; ++j) { e[j] = __expf(x[j] - m); s += e[j]; }
#pragma unroll
    for (int off = 32; off > 0; off >>= 1) s += __shfl_xor(s, off);
    if (lane == 0) red[4 + wid] = s;
    __syncthreads();
    s = red[4] + red[5] + red[6] + red[7];
    const float inv = 1.f / s;

    short8 o;
#pragma unroll
    for (int j = 0; j < 8; ++j) o[j] = (short)f2bf(e[j] * inv);
    *(short8*)(p + tid * 8) = o;
}

// bf16 transpose: in [z][R][C] -> out [z][C][R], 64x64 LDS tiles.
__global__ __launch_bounds__(256) void transpose_bf16(
    const u16* __restrict__ in, u16* __restrict__ out, int R, int C)
{
    __shared__ u16 t[64][72];  // +8 pad breaks column-read conflicts
    const long z = blockIdx.z;
    in  += z * (long)R * C;
    out += z * (long)R * C;
    const int r0 = blockIdx.y * 64, c0 = blockIdx.x * 64;
    const int tid = threadIdx.x;

    const int r = tid >> 2, cc = (tid & 3) * 16;
    const short8* src = (const short8*)(in + (long)(r0 + r) * C + c0 + cc);
    short8 v0 = src[0], v1 = src[1];
#pragma unroll
    for (int j = 0; j < 8; ++j) {
        t[r][cc + j]     = (u16)v0[j];
        t[r][cc + 8 + j] = (u16)v1[j];
    }
    __syncthreads();

    const int c = tid >> 2, rr = (tid & 3) * 16;
    short8 o0, o1;
#pragma unroll
    for (int j = 0; j < 8; ++j) {
        o0[j] = (short)t[rr + j][c];
        o1[j] = (short)t[rr + 8 + j][c];
    }
    short8* dst = (short8*)(out + (long)(c0 + c) * R + r0 + rr);
    dst[0] = o0;
    dst[1] = o1;
}

extern "C" void kernel_launch(void* const* d_in, const int* in_sizes, int n_in,
                              void* d_out, int out_size, void* d_ws, size_t ws_size,
                              hipStream_t stream) {
    const float* q  = (const float*)d_in[0];
    const float* k  = (const float*)d_in[1];
    const float* v  = (const float*)d_in[2];
    const float* Wq = (const float*)d_in[3];
    const float* bq = (const float*)d_in[4];
    const float* Wk = (const float*)d_in[5];
    const float* bk = (const float*)d_in[6];
    const float* Wv = (const float*)d_in[7];
    const float* bv = (const float*)d_in[8];

    const int S = 2048, D = 1024;          // B = 4
    const long MiB = 1024L * 1024L;
    const long nQ = 4L * S * D;            // 8.39M elems
    const long nW = (long)D * D;           // 1.05M elems
    char* ws = (char*)d_ws;
    u16* sb  = (u16*)(ws + 0 * MiB);
    u16* wb  = (u16*)(ws + 16 * MiB);
    u16* qp  = (u16*)(ws + 18 * MiB);
    u16* kp  = (u16*)(ws + 34 * MiB);
    u16* vp  = (u16*)(ws + 50 * MiB);
    u16* P   = (u16*)(ws + 66 * MiB);      // 32 MiB
    u16* vpT = (u16*)(ws + 0 * MiB);       // reuses sb

    dim3 blk(256);
    dim3 gproj(8, 64, 1);

    // q-projection
    cvt2<<<dim3(512, 1, 2), blk, 0, stream>>>(q, sb, nQ, Wq, wb, nW);
    gemm_bt<true, true><<<gproj, blk, 0, stream>>>(sb, wb, bq, qp,
        8192, 1024, 1024, 0, 0, 0, 1.f);
    // k-projection
    cvt2<<<dim3(512, 1, 2), blk, 0, stream>>>(k, sb, nQ, Wk, wb, nW);
    gemm_bt<true, true><<<gproj, blk, 0, stream>>>(sb, wb, bk, kp,
        8192, 1024, 1024, 0, 0, 0, 1.f);
    // v-projection
    cvt2<<<dim3(512, 1, 2), blk, 0, stream>>>(v, sb, nQ, Wv, wb, nW);
    gemm_bt<true, true><<<gproj, blk, 0, stream>>>(sb, wb, bv, vp,
        8192, 1024, 1024, 0, 0, 0, 1.f);

    // vpT[b] = vp[b]^T   ([2048,1024] -> [1024,2048]); sb is dead now
    transpose_bf16<<<dim3(16, 32, 4), blk, 0, stream>>>(vp, vpT, S, D);

    // E = qp @ kp^T / 32, per batch
    gemm_bt<true, false><<<dim3(16, 16, 4), blk, 0, stream>>>(qp, kp, nullptr, P,
        2048, 2048, 1024, (long)S * D, (long)S * D, (long)S * S, 0.03125f);

    // P = softmax(E) rows, in place
    softmax_rows<<<dim3(4 * S), blk, 0, stream>>>(P, S);

    // out = P @ vpT^T (fp32 out)
    gemm_bt<false, false><<<dim3(8, 16, 4), blk, 0, stream>>>(P, vpT, nullptr,
        (float*)d_out, 2048, 1024, 2048, (long)S * S, (long)D * S, (long)S * D, 1.f);
}

// Round 6
// 369.720 us; speedup vs baseline: 1.1195x; 1.0563x over previous
//
#include <hip/hip_runtime.h>
#include <hip/hip_bf16.h>

// SelfAttention: qp = q@Wq^T+bq (k,v likewise); E = qp kp^T/32; P = softmax(E);
// out = P vp.   B=4, S=2048, D=1024, fp32 in/out.
//
// GEMMs: 256x256 tile, BK=64, 8 waves (2Mx4N), 512 thr, 128 KiB LDS dbuf,
// 8-phase schedule (4 phases/K-tile), counted vmcnt(4) once per K-tile,
// LDS 16B-slot XOR swizzle (linear gload_lds dest + pre-swizzled global src),
// setprio around MFMA clusters, bijective XCD blockIdx swizzle.
//
// Workspace (98 MiB):
//   sb   bf16 [8192,1024]  @  0 MiB  (q/k/v staging, reused; vpT later)
//   wb   bf16 [1024,1024]  @ 16 MiB  (W staging, reused)
//   qp/kp/vp bf16 [4,2048,1024] @ 18/34/50 MiB
//   P    bf16 [4,2048,2048]@ 66 MiB  (E -> softmax in place)
//   vpT  bf16 [4,1024,2048]@  0 MiB  (over sb)

typedef unsigned short u16;
typedef __attribute__((ext_vector_type(8))) short short8;
typedef __attribute__((ext_vector_type(4))) float f32x4;

typedef const __attribute__((address_space(1))) void* gptr_t;
typedef __attribute__((address_space(3))) void* sptr_t;

static __device__ __forceinline__ u16 f2bf(float f) {
    unsigned u = __float_as_uint(f);
    u += 0x7FFFu + ((u >> 16) & 1u);   // RNE
    return (u16)(u >> 16);
}
static __device__ __forceinline__ float bf2f(u16 s) {
    return __uint_as_float(((unsigned)s) << 16);
}
static __device__ __forceinline__ void gll16(const void* g, void* l) {
    __builtin_amdgcn_global_load_lds((gptr_t)g, (sptr_t)l, 16, 0, 0);
}

#define CFENCE asm volatile("" ::: "memory")
#define SBAR do { CFENCE; __builtin_amdgcn_sched_barrier(0); \
                  __builtin_amdgcn_s_barrier(); \
                  __builtin_amdgcn_sched_barrier(0); CFENCE; } while (0)

// fp32 -> bf16 for two tensors, z selects. 8 elems/thr/iter.
__global__ __launch_bounds__(256) void cvt2(
    const float* __restrict__ a, u16* __restrict__ oa, long na,
    const float* __restrict__ b, u16* __restrict__ ob, long nb)
{
    const float* s = blockIdx.z ? b : a;
    u16* d = blockIdx.z ? ob : oa;
    const long n = blockIdx.z ? nb : na;
    const long stride = (long)gridDim.x * blockDim.x * 8;
    for (long i = ((long)blockIdx.x * blockDim.x + threadIdx.x) * 8; i < n; i += stride) {
        f32x4 x = *(const f32x4*)(s + i);
        f32x4 y = *(const f32x4*)(s + i + 4);
        short8 o;
#pragma unroll
        for (int j = 0; j < 4; ++j) { o[j] = (short)f2bf(x[j]); o[4 + j] = (short)f2bf(y[j]); }
        *(short8*)(d + i) = o;
    }
}

// C = scale*(A @ B^T) + bias. A: bf16 [*,lda] rows row0.., B: bf16 [*,ldb]
// rows col0.., C: [*,ldc]. 256x256 tile, 8-phase pipeline, K%64==0.
template <bool OUT_BF16, bool HAS_BIAS>
__global__ __launch_bounds__(512, 2) void gemm256(
    const u16* __restrict__ A, const u16* __restrict__ B,
    const float* __restrict__ bias, void* __restrict__ Cv,
    int K, int lda, int ldb, int ldc, long sA, long sB, long sC, float scale)
{
    extern __shared__ char lds[];   // 128 KiB: [buf][A 32K | B 32K]
    const int tid = threadIdx.x;
    const int lane = tid & 63, wid = tid >> 6;

    // bijective XCD swizzle on linearized block id (grid sizes are %8==0)
    const int gx = gridDim.x, gy = gridDim.y;
    const int nwg = gx * gy * gridDim.z;
    int bid = blockIdx.x + gx * (blockIdx.y + gy * blockIdx.z);
    const int cpx = nwg >> 3;
    bid = (bid & 7) * cpx + (bid >> 3);
    const int bx = bid % gx;
    const int rem = bid / gx;
    const int by = rem % gy;
    const long bz = rem / gy;
    A += bz * sA;
    B += bz * sB;
    const int row0 = by * 256, col0 = bx * 256;

    const int wr = wid >> 2, wc = wid & 3;     // 2x4 wave grid; 128x64 out/wave
    const int fq = lane >> 4, fr = lane & 15;

    // fragment-read byte offsets (swizzled 16B slot = (kk*4+fq) ^ (row&7))
    const int slot0 = ((fq) ^ (fr & 7)) << 4;
    const int slot1 = ((4 + fq) ^ (fr & 7)) << 4;
    const int aBase = (wr * 128 + fr) * 128;
    const int bBase = 32768 + (wc * 64 + fr) * 128;

    // staging lane geometry: linear LDS dest + inverse-swizzled global col
    const int sgRow = lane >> 3;                    // 0..7
    const int sgColB = ((lane & 7) ^ sgRow) << 4;   // global col byte
    const int asub = wid & 3;                       // A-quarter stager sub-id

    // stage A-quarter (rows wr*128+q*64..+64) of K-tile T -> buf[T&1]
#define STAGE_A(T, Q) do { \
    char* d_ = lds + (((T) & 1) << 16) + ((wr * 128 + (Q) * 64) * 128) + asub * 2048; \
    const char* s_ = (const char*)(A + (long)(row0 + wr * 128 + (Q) * 64 + asub * 16 + sgRow) * lda + (T) * 64) + sgColB; \
    gll16(s_, d_); \
    gll16(s_ + (long)8 * lda * 2, d_ + 1024); \
} while (0)
    // stage B-quarter (rows wc*64+q*32..+32)
#define STAGE_B(T, Q) do { \
    char* d_ = lds + (((T) & 1) << 16) + 32768 + ((wc * 64 + (Q) * 32) * 128) + wr * 2048; \
    const char* s_ = (const char*)(B + (long)(col0 + wc * 64 + (Q) * 32 + wr * 16 + sgRow) * ldb + (T) * 64) + sgColB; \
    gll16(s_, d_); \
    gll16(s_ + (long)8 * ldb * 2, d_ + 1024); \
} while (0)

#define RDA(MIBASE) do { \
    const char* p_ = bufc + aBase + (MIBASE) * 2048; \
    _Pragma("unroll") for (int mi_ = 0; mi_ < 4; ++mi_) { \
        af[mi_ * 2 + 0] = *(const short8*)(p_ + mi_ * 2048 + slot0); \
        af[mi_ * 2 + 1] = *(const short8*)(p_ + mi_ * 2048 + slot1); \
    } \
} while (0)
#define RDB(NIBASE) do { \
    const char* p_ = bufc + bBase + (NIBASE) * 2048; \
    _Pragma("unroll") for (int ni_ = 0; ni_ < 2; ++ni_) { \
        bf[ni_ * 2 + 0] = *(const short8*)(p_ + ni_ * 2048 + slot0); \
        bf[ni_ * 2 + 1] = *(const short8*)(p_ + ni_ * 2048 + slot1); \
    } \
} while (0)

#define QUAD(QM, QN) do { \
    __builtin_amdgcn_s_setprio(1); \
    _Pragma("unroll") for (int mi_ = 0; mi_ < 4; ++mi_) \
    _Pragma("unroll") for (int ni_ = 0; ni_ < 2; ++ni_) { \
        acc[(QM) * 4 + mi_][(QN) * 2 + ni_] = __builtin_amdgcn_mfma_f32_16x16x32_bf16( \
            af[mi_ * 2 + 0], bf[ni_ * 2 + 0], acc[(QM) * 4 + mi_][(QN) * 2 + ni_], 0, 0, 0); \
        acc[(QM) * 4 + mi_][(QN) * 2 + ni_] = __builtin_amdgcn_mfma_f32_16x16x32_bf16( \
            af[mi_ * 2 + 1], bf[ni_ * 2 + 1], acc[(QM) * 4 + mi_][(QN) * 2 + ni_], 0, 0, 0); \
    } \
    __builtin_amdgcn_s_setprio(0); \
} while (0)

    f32x4 acc[8][4] = {};
    short8 af[8], bf[4];
    const int NT = K >> 6;

    // prologue: tile0 all quarters + tile1 A-quarters; leave tile1's A in flight
    STAGE_A(0, 0); STAGE_A(0, 1); STAGE_B(0, 0); STAGE_B(0, 1);
    if (NT > 1) {
        STAGE_A(1, 0); STAGE_A(1, 1);
        asm volatile("s_waitcnt vmcnt(4)" ::: "memory");
    } else {
        asm volatile("s_waitcnt vmcnt(0)" ::: "memory");
    }
    SBAR;

    for (int t = 0; t < NT; ++t) {
        const char* bufc = lds + ((t & 1) << 16);
        // P0: quad(0,0)  reads Aq0,Bq0 | stages Bq0,Bq1(t+1)
        RDA(0); RDB(0);
        if (t + 1 < NT) { STAGE_B(t + 1, 0); STAGE_B(t + 1, 1); }
        SBAR; QUAD(0, 0); SBAR;
        // P1: quad(0,1)  reads Bq1 | stages Aq0(t+2)
        RDB(2);
        if (t + 2 < NT) STAGE_A(t + 2, 0);
        SBAR; QUAD(0, 1); SBAR;
        // P2: quad(1,1)  reads Aq1
        RDA(4);
        SBAR; QUAD(1, 1); SBAR;
        // P3: quad(1,0)  re-reads Bq0 | stages Aq1(t+2) | counted vmcnt
        RDB(0);
        if (t + 2 < NT) STAGE_A(t + 2, 1);
        if (t < NT - 2) asm volatile("s_waitcnt vmcnt(4)" ::: "memory");
        else            asm volatile("s_waitcnt vmcnt(0)" ::: "memory");
        SBAR; QUAD(1, 0); SBAR;
    }

    float bcol[4];
#pragma unroll
    for (int ni = 0; ni < 4; ++ni)
        bcol[ni] = HAS_BIAS ? bias[col0 + wc * 64 + ni * 16 + fr] : 0.f;

    // C/D layout (m89-verified): col = lane&15, row = (lane>>4)*4 + j
#pragma unroll
    for (int mi = 0; mi < 8; ++mi) {
#pragma unroll
        for (int ni = 0; ni < 4; ++ni) {
            const int cc = col0 + wc * 64 + ni * 16 + fr;
#pragma unroll
            for (int j = 0; j < 4; ++j) {
                const int rr = row0 + wr * 128 + mi * 16 + fq * 4 + j;
                const float vv = acc[mi][ni][j] * scale + bcol[ni];
                if constexpr (OUT_BF16) {
                    ((u16*)Cv)[bz * sC + (long)rr * ldc + cc] = f2bf(vv);
                } else {
                    ((float*)Cv)[bz * sC + (long)rr * ldc + cc] = vv;
                }
            }
        }
    }
#undef STAGE_A
#undef STAGE_B
#undef RDA
#undef RDB
#undef QUAD
}

// In-place row softmax on bf16 [rows][S], S = 2048, one 256-thr block per row.
__global__ __launch_bounds__(256) void softmax_rows(u16* __restrict__ P, int S) {
    const long row = blockIdx.x;
    u16* p = P + row * (long)S;
    const int tid = threadIdx.x;
    const int wid = tid >> 6, lane = tid & 63;

    short8 v = *(const short8*)(p + tid * 8);
    float x[8];
#pragma unroll
    for (int j = 0; j < 8; ++j) x[j] = bf2f((u16)v[j]);

    float m = x[0];
#pragma unroll
    for (int j = 1; j < 8; ++j) m = fmaxf(m, x[j]);
#pragma unroll
    for (int off = 32; off > 0; off >>= 1) m = fmaxf(m, __shfl_xor(m, off));
    __shared__ float red[8];
    if (lane == 0) red[wid] = m;
    __syncthreads();
    m = fmaxf(fmaxf(red[0], red[1]), fmaxf(red[2], red[3]));

    float e[8], s = 0.f;
#pragma unroll
    for (int j = 0; j < 8; ++j) { e[j] = __expf(x[j] - m); s += e[j]; }
#pragma unroll
    for (int off = 32; off > 0; off >>= 1) s += __shfl_xor(s, off);
    if (lane == 0) red[4 + wid] = s;
    __syncthreads();
    s = red[4] + red[5] + red[6] + red[7];
    const float inv = 1.f / s;

    short8 o;
#pragma unroll
    for (int j = 0; j < 8; ++j) o[j] = (short)f2bf(e[j] * inv);
    *(short8*)(p + tid * 8) = o;
}

// bf16 transpose: in [z][R][C] -> out [z][C][R], 64x64 LDS tiles.
__global__ __launch_bounds__(256) void transpose_bf16(
    const u16* __restrict__ in, u16* __restrict__ out, int R, int C)
{
    __shared__ u16 t[64][72];
    const long z = blockIdx.z;
    in  += z * (long)R * C;
    out += z * (long)R * C;
    const int r0 = blockIdx.y * 64, c0 = blockIdx.x * 64;
    const int tid = threadIdx.x;

    const int r = tid >> 2, cc = (tid & 3) * 16;
    const short8* src = (const short8*)(in + (long)(r0 + r) * C + c0 + cc);
    short8 v0 = src[0], v1 = src[1];
#pragma unroll
    for (int j = 0; j < 8; ++j) {
        t[r][cc + j]     = (u16)v0[j];
        t[r][cc + 8 + j] = (u16)v1[j];
    }
    __syncthreads();

    const int c = tid >> 2, rr = (tid & 3) * 16;
    short8 o0, o1;
#pragma unroll
    for (int j = 0; j < 8; ++j) {
        o0[j] = (short)t[rr + j][c];
        o1[j] = (short)t[rr + 8 + j][c];
    }
    short8* dst = (short8*)(out + (long)(c0 + c) * R + r0 + rr);
    dst[0] = o0;
    dst[1] = o1;
}

extern "C" void kernel_launch(void* const* d_in, const int* in_sizes, int n_in,
                              void* d_out, int out_size, void* d_ws, size_t ws_size,
                              hipStream_t stream) {
    const float* q  = (const float*)d_in[0];
    const float* k  = (const float*)d_in[1];
    const float* v  = (const float*)d_in[2];
    const float* Wq = (const float*)d_in[3];
    const float* bq = (const float*)d_in[4];
    const float* Wk = (const float*)d_in[5];
    const float* bk = (const float*)d_in[6];
    const float* Wv = (const float*)d_in[7];
    const float* bv = (const float*)d_in[8];

    const int S = 2048, D = 1024;          // B = 4
    const long MiB = 1024L * 1024L;
    const long nQ = 4L * S * D;
    const long nW = (long)D * D;
    char* ws = (char*)d_ws;
    u16* sb  = (u16*)(ws + 0 * MiB);
    u16* wb  = (u16*)(ws + 16 * MiB);
    u16* qp  = (u16*)(ws + 18 * MiB);
    u16* kp  = (u16*)(ws + 34 * MiB);
    u16* vp  = (u16*)(ws + 50 * MiB);
    u16* P   = (u16*)(ws + 66 * MiB);      // 32 MiB
    u16* vpT = (u16*)(ws + 0 * MiB);       // reuses sb

    const int LDSB = 131072;
    hipFuncSetAttribute(reinterpret_cast<const void*>(&gemm256<true, true>),
                        hipFuncAttributeMaxDynamicSharedMemorySize, LDSB);
    hipFuncSetAttribute(reinterpret_cast<const void*>(&gemm256<true, false>),
                        hipFuncAttributeMaxDynamicSharedMemorySize, LDSB);
    hipFuncSetAttribute(reinterpret_cast<const void*>(&gemm256<false, false>),
                        hipFuncAttributeMaxDynamicSharedMemorySize, LDSB);

    dim3 blk(256), gblk(512);
    dim3 gproj(4, 32, 1);                  // N=1024, M=8192

    // q-projection
    cvt2<<<dim3(512, 1, 2), blk, 0, stream>>>(q, sb, nQ, Wq, wb, nW);
    gemm256<true, true><<<gproj, gblk, LDSB, stream>>>(sb, wb, bq, qp,
        1024, 1024, 1024, 1024, 0, 0, 0, 1.f);
    // k-projection
    cvt2<<<dim3(512, 1, 2), blk, 0, stream>>>(k, sb, nQ, Wk, wb, nW);
    gemm256<true, true><<<gproj, gblk, LDSB, stream>>>(sb, wb, bk, kp,
        1024, 1024, 1024, 1024, 0, 0, 0, 1.f);
    // v-projection
    cvt2<<<dim3(512, 1, 2), blk, 0, stream>>>(v, sb, nQ, Wv, wb, nW);
    gemm256<true, true><<<gproj, gblk, LDSB, stream>>>(sb, wb, bv, vp,
        1024, 1024, 1024, 1024, 0, 0, 0, 1.f);

    // vpT[b] = vp[b]^T  ([2048,1024] -> [1024,2048]); sb dead now
    transpose_bf16<<<dim3(16, 32, 4), blk, 0, stream>>>(vp, vpT, S, D);

    // E = qp @ kp^T / 32, per batch
    gemm256<true, false><<<dim3(8, 8, 4), gblk, LDSB, stream>>>(qp, kp, nullptr, P,
        1024, 1024, 1024, 2048, (long)S * D, (long)S * D, (long)S * S, 0.03125f);

    // P = softmax(E) rows, in place
    softmax_rows<<<dim3(4 * S), blk, 0, stream>>>(P, S);

    // out = P @ vpT^T (fp32 out)
    gemm256<false, false><<<dim3(4, 8, 4), gblk, LDSB, stream>>>(P, vpT, nullptr,
        (float*)d_out, 2048, 2048, 2048, 1024, (long)S * S, (long)D * S, (long)S * D, 1.f);
}